// Round 4
// baseline (1579.684 us; speedup 1.0000x reference)
//
#include <hip/hip_runtime.h>
#include <hip/hip_bf16.h>
#include <math.h>

// D_MODEL=1024, D_INNER=2048, NHEADS=32, HEADDIM=64, CHUNK=64, B=4, L=4096
// C == ones collapses the state dim -> scalar scan per (h,p) channel.
// GEMMs: bf16x3 split MFMA (Ah*Bh + Ah*Bl + Al*Bh), fp32-equivalent.
// This round: NO LDS in the GEMMs. Operands pre-packed in MFMA fragment
// order (frag[lane] = M[tile*16+(lane&15)][(lane>>4)*8..+8]) so every
// fragment is one coalesced global_load_dwordx4; no barriers in the K-loop.
//
// Workspace (102.7 MB, == round-2-certified footprint):
//  R0 32MiB: zh/zl row-major           [gemm1 -> passC]
//  R1 32MiB: xch/xcl row-major [gemm1->scanA], then ypacked h/l [passC->gemm2]
//  R2 32MiB: w1packed(17.3MB)[->gemm1] -> ylh/yll(32MiB)[scanA->passC]
//            -> w2packed(8.4MB)[->gemm2]   (cycled per batch)
//  tail ~2MB: dtraw, decay, Fb, Eb, Sprev

typedef __attribute__((ext_vector_type(8))) short bf16x8;
typedef __attribute__((ext_vector_type(4))) float f32x4;

__device__ __forceinline__ float bf2f(unsigned short u) {
    union { float f; unsigned int i; } x; x.i = ((unsigned int)u) << 16; return x.f;
}
__device__ __forceinline__ unsigned short f2bf(float f) {  // RNE
    union { float f; unsigned int i; } x; x.f = f;
    unsigned int r = x.i + 0x7fffu + ((x.i >> 16) & 1u);
    return (unsigned short)(r >> 16);
}
__device__ __forceinline__ float softplusf(float x) {
    return (x > 20.f) ? x : log1pf(expf(x));
}
__device__ __forceinline__ float silu_mod(float x) {  // sigmoid(x)+0.1x per ref
    return 1.f / (1.f + expf(-x)) + 0.1f * x;
}
// packed split: (x,y) -> hi pair (2xbf16 in uint) + lo pair
__device__ __forceinline__ void cvt_split2(float x, float y,
                                           unsigned int* hi, unsigned int* lo) {
    __hip_bfloat162 h2 = __float22bfloat162_rn(make_float2(x, y));
    unsigned int h; __builtin_memcpy(&h, &h2, 4);
    union { float f; unsigned int i; } fx, fy;
    fx.i = h << 16;
    fy.i = h & 0xffff0000u;
    __hip_bfloat162 l2 = __float22bfloat162_rn(make_float2(x - fx.f, y - fy.f));
    unsigned int l; __builtin_memcpy(&l, &l2, 4);
    *hi = h; *lo = l;
}
__device__ __forceinline__ void split4(float4 v, ushort4* h, ushort4* l) {
    unsigned short t;
    t = f2bf(v.x); h->x = t; l->x = f2bf(v.x - bf2f(t));
    t = f2bf(v.y); h->y = t; l->y = f2bf(v.y - bf2f(t));
    t = f2bf(v.z); h->z = t; l->z = f2bf(v.z - bf2f(t));
    t = f2bf(v.w); h->w = t; l->w = f2bf(v.w - bf2f(t));
}

// ---------------------------------------------------------------------------
// pack weights row-major fp32 -> fragment-order split bf16.
// chunk t covers (tile = t>>(6+KCN_LOG), kc = (t>>6)&(KCN-1), lane = t&63):
//   data = src[tile*16 + (lane&15)][kc*32 + (lane>>4)*8 .. +8]
// REMAP (in_w): row<4096 -> row; 4096..4127 -> row+128 (dt cols); else zero.
// ---------------------------------------------------------------------------
template <int KCN_LOG, int REMAP>
__global__ __launch_bounds__(256) void pack_split(
    const float* __restrict__ src, int src_ld,
    unsigned short* __restrict__ h, unsigned short* __restrict__ l)
{
    int t = blockIdx.x * 256 + threadIdx.x;
    int lane = t & 63;
    int kc = (t >> 6) & ((1 << KCN_LOG) - 1);
    int tile = t >> (6 + KCN_LOG);
    int n = tile * 16 + (lane & 15);
    int k = kc * 32 + (lane >> 4) * 8;
    int sr = n;
    if (REMAP) sr = (n < 4096) ? n : (n < 4128 ? n + 128 : -1);
    float4 v0 = make_float4(0.f, 0.f, 0.f, 0.f), v1 = v0;
    if (sr >= 0) {
        const float* s = src + (size_t)sr * src_ld + k;
        v0 = *(const float4*)s;
        v1 = *(const float4*)(s + 4);
    }
    ushort4 h0, l0, h1, l1;
    split4(v0, &h0, &l0);
    split4(v1, &h1, &l1);
    size_t o = (size_t)t * 8;
    *(ushort4*)(h + o) = h0; *(ushort4*)(h + o + 4) = h1;
    *(ushort4*)(l + o) = l0; *(ushort4*)(l + o + 4) = l1;
}

// ---------------------------------------------------------------------------
// LDS-free bf16x3 MFMA NT-GEMM. 128x128 block, 256 thr = 4 waves (2x2),
// each wave 4x4 tiles of 16x16x32. B always fragment-packed.
// MODE 0: A = fp32 row-major (direct loads + in-register split);
//         split-stores z/xc row-major + dtraw.
// MODE 1: A = fragment-packed split bf16; fp32 out.
// ---------------------------------------------------------------------------
template <int MODE, int KDIM>
__global__ __launch_bounds__(256, 2) void mfma_gemm(
    const float* __restrict__ Af,
    const unsigned short* __restrict__ Aph, const unsigned short* __restrict__ Apl,
    const unsigned short* __restrict__ Bph, const unsigned short* __restrict__ Bpl,
    const float* __restrict__ bias,
    unsigned short* __restrict__ zh, unsigned short* __restrict__ zl,
    unsigned short* __restrict__ xch, unsigned short* __restrict__ xcl,
    float* __restrict__ dtraw, float* __restrict__ outC)
{
    constexpr int KCN = KDIM / 32;
    const int tid = threadIdx.x;
    const int lane = tid & 63, w = tid >> 6;
    const int wm = w & 1, wn = w >> 1;
    const int m0 = blockIdx.y * 128, n0 = blockIdx.x * 128;
    const int fr = lane & 15, q = lane >> 4;

    // B fragment pointers (advance 512 shorts per k-step)
    const unsigned short* bhp[4];
    const unsigned short* blp[4];
#pragma unroll
    for (int nt = 0; nt < 4; nt++) {
        size_t c = ((size_t)((n0 >> 4) + wn * 4 + nt) * KCN * 64 + lane) * 8;
        bhp[nt] = Bph + c;
        blp[nt] = Bpl + c;
    }
    // A pointers
    const float* afp[4];
    const unsigned short* ahp[4];
    const unsigned short* alp[4];
#pragma unroll
    for (int mt = 0; mt < 4; mt++) {
        if (MODE == 0) {
            afp[mt] = Af + (size_t)(m0 + wm * 64 + mt * 16 + fr) * KDIM + q * 8;
        } else {
            size_t c = ((size_t)((m0 >> 4) + wm * 4 + mt) * KCN * 64 + lane) * 8;
            ahp[mt] = Aph + c;
            alp[mt] = Apl + c;
        }
    }

    f32x4 acc[4][4];
#pragma unroll
    for (int i = 0; i < 4; i++)
#pragma unroll
        for (int j = 0; j < 4; j++) acc[i][j] = (f32x4){0.f, 0.f, 0.f, 0.f};

#pragma unroll 2
    for (int kc = 0; kc < KCN; kc++) {
        bf16x8 a_h[4], a_l[4], b_h[4], b_l[4];
#pragma unroll
        for (int nt = 0; nt < 4; nt++) {
            b_h[nt] = *(const bf16x8*)bhp[nt];
            b_l[nt] = *(const bf16x8*)blp[nt];
            bhp[nt] += 512;
            blp[nt] += 512;
        }
#pragma unroll
        for (int mt = 0; mt < 4; mt++) {
            if (MODE == 0) {
                float4 a0 = *(const float4*)afp[mt];
                float4 a1 = *(const float4*)(afp[mt] + 4);
                afp[mt] += 32;
                union { bf16x8 v; unsigned int u[4]; } H, L;
                cvt_split2(a0.x, a0.y, &H.u[0], &L.u[0]);
                cvt_split2(a0.z, a0.w, &H.u[1], &L.u[1]);
                cvt_split2(a1.x, a1.y, &H.u[2], &L.u[2]);
                cvt_split2(a1.z, a1.w, &H.u[3], &L.u[3]);
                a_h[mt] = H.v; a_l[mt] = L.v;
            } else {
                a_h[mt] = *(const bf16x8*)ahp[mt];
                a_l[mt] = *(const bf16x8*)alp[mt];
                ahp[mt] += 512;
                alp[mt] += 512;
            }
        }
#pragma unroll
        for (int mt = 0; mt < 4; mt++)
#pragma unroll
            for (int nt = 0; nt < 4; nt++) {
                acc[mt][nt] = __builtin_amdgcn_mfma_f32_16x16x32_bf16(
                    a_h[mt], b_h[nt], acc[mt][nt], 0, 0, 0);
                acc[mt][nt] = __builtin_amdgcn_mfma_f32_16x16x32_bf16(
                    a_h[mt], b_l[nt], acc[mt][nt], 0, 0, 0);
                acc[mt][nt] = __builtin_amdgcn_mfma_f32_16x16x32_bf16(
                    a_l[mt], b_h[nt], acc[mt][nt], 0, 0, 0);
            }
    }

    // epilogue: D[row=q*4+reg][col=fr] per 16x16 tile
#pragma unroll
    for (int nt = 0; nt < 4; nt++) {
        int jn = n0 + wn * 64 + nt * 16 + fr;
        if (MODE == 0 && jn >= 4128) continue;
        float bv = 0.f;
        if (MODE == 0) bv = bias[jn < 4096 ? jn : jn + 128];
#pragma unroll
        for (int mt = 0; mt < 4; mt++) {
#pragma unroll
            for (int reg = 0; reg < 4; reg++) {
                int rm = m0 + wm * 64 + mt * 16 + q * 4 + reg;
                float v = acc[mt][nt][reg] + bv;
                if (MODE == 0) {
                    if (jn < 2048) {
                        size_t o = (size_t)rm * 2048 + jn;
                        unsigned short hh = f2bf(v);
                        zh[o] = hh; zl[o] = f2bf(v - bf2f(hh));
                    } else if (jn < 4096) {
                        size_t o = (size_t)rm * 2048 + (jn - 2048);
                        unsigned short hh = f2bf(v);
                        xch[o] = hh; xcl[o] = f2bf(v - bf2f(hh));
                    } else {
                        dtraw[(size_t)rm * 32 + (jn - 4096)] = v;
                    }
                } else {
                    outC[(size_t)rm * 1024 + jn] = v;
                }
            }
        }
    }
}

// ---------------------------------------------------------------------------
// scanA: one batch. Per (h, chunk) block, 64 threads (p). conv4 + silu' +
// softplus(dt) + decay cumsum + 64-step local scan. xc/ylocal split bf16.
// ---------------------------------------------------------------------------
__global__ __launch_bounds__(64) void scanA(
    const unsigned short* __restrict__ xch, const unsigned short* __restrict__ xcl,
    const float* __restrict__ dtraw, const float* __restrict__ reward,
    const float* __restrict__ conv_w, const float* __restrict__ conv_b,
    const float* __restrict__ dt_bias, const float* __restrict__ A_log,
    const float* __restrict__ bw, const float* __restrict__ bb,
    unsigned short* __restrict__ ylh, unsigned short* __restrict__ yll,
    float* __restrict__ decay, float* __restrict__ Fb, float* __restrict__ Eb)
{
    const int blk = blockIdx.x;        // h*64 + t
    const int t = blk & 63;
    const int h = blk >> 6;
    const int p = threadIdx.x;
    const int l0 = t * 64;

    __shared__ float xs[67][65];
    __shared__ float gbuf[64], ebuf[64], dtbuf[64];
    __shared__ float cum63;

    float v1 = bw[p] + bw[p + 64];
    float v2 = bb[p] + bb[p + 64];
#pragma unroll
    for (int o = 32; o > 0; o >>= 1) {
        v1 += __shfl_down(v1, o, 64);
        v2 += __shfl_down(v2, o, 64);
    }
    const float sbw = __shfl(v1, 0, 64);
    const float sbb = __shfl(v2, 0, 64);

    const int l = l0 + p;
    const float dt = softplusf(dtraw[(size_t)l * 32 + h] + dt_bias[h]);
    const float a = -expf(A_log[h]) * dt;
    float cum = a;
#pragma unroll
    for (int o = 1; o < 64; o <<= 1) {
        float uo = __shfl_up(cum, o, 64);
        if (p >= o) cum += uo;
    }
    decay[(size_t)l * 32 + h] = expf(cum);
    gbuf[p] = reward[l] * sbw + sbb;
    ebuf[p] = expf(a);
    dtbuf[p] = dt;
    if (p == 63) cum63 = cum;

    const int c = h * 64 + p;
    for (int r = 0; r < 67; r++) {
        int ls = l0 - 3 + r;
        float x = 0.f;
        if (ls >= 0) {
            size_t o = (size_t)ls * 2048 + c;
            x = bf2f(xch[o]) + bf2f(xcl[o]);
        }
        xs[r][p] = x;
    }
    __syncthreads();

    const float w0 = conv_w[c * 4 + 0], w1 = conv_w[c * 4 + 1],
                w2 = conv_w[c * 4 + 2], w3 = conv_w[c * 4 + 3];
    const float cb = conv_b[c];
    float y = 0.f;
    size_t outp = (size_t)l0 * 2048 + c;
#pragma unroll 4
    for (int i = 0; i < 64; i++) {
        float v = cb + xs[i][p] * w0 + xs[i + 1][p] * w1 +
                  xs[i + 2][p] * w2 + xs[i + 3][p] * w3;
        float xdt = silu_mod(v) * dtbuf[i];
        y = y * ebuf[i] + gbuf[i] * xdt;
        unsigned short hh = f2bf(y);
        ylh[outp] = hh;
        yll[outp] = f2bf(y - bf2f(hh));
        outp += 2048;
    }
    Fb[((size_t)h * 64 + t) * 64 + p] = y;
    if (p == 0) Eb[(size_t)h * 64 + t] = expf(cum63);
}

// ---------------------------------------------------------------------------
__global__ void scanB(const float* __restrict__ Fb, const float* __restrict__ Eb,
                      float* __restrict__ Sprev)
{
    int idx = blockIdx.x * blockDim.x + threadIdx.x;  // 2048
    int p = idx & 63;
    int h = idx >> 6;
    int base = h * 64;
    float S = 0.f;
    for (int t = 0; t < 64; t++) {
        Sprev[(size_t)(base + t) * 64 + p] = S;
        S = S * Eb[base + t] + Fb[(size_t)(base + t) * 64 + p];
    }
}

// ---------------------------------------------------------------------------
// passC: y = (ylocal + S*decay) * silu_mod(z), emitted split bf16 directly in
// gemm2's A fragment-packed order (KCN=64).
// ---------------------------------------------------------------------------
__global__ __launch_bounds__(256) void passC(
    const unsigned short* __restrict__ ylh, const unsigned short* __restrict__ yll,
    const unsigned short* __restrict__ zh, const unsigned short* __restrict__ zl,
    const float* __restrict__ Sprev, const float* __restrict__ decay,
    unsigned short* __restrict__ yph, unsigned short* __restrict__ ypl)
{
    size_t idx = ((size_t)blockIdx.x * 256 + threadIdx.x) * 4;
    int row = (int)(idx >> 11);
    int cc = (int)(idx & 2047);
    int t = row >> 6;
    int h = cc >> 6, p = cc & 63;
    ushort4 ah = *(const ushort4*)(ylh + idx);
    ushort4 al = *(const ushort4*)(yll + idx);
    ushort4 bh = *(const ushort4*)(zh + idx);
    ushort4 bl = *(const ushort4*)(zl + idx);
    float4 sv = *(const float4*)(Sprev + ((size_t)(h * 64 + t)) * 64 + p);
    float d = decay[(size_t)row * 32 + h];
    float4 yv;
    yv.x = (bf2f(ah.x) + bf2f(al.x) + sv.x * d) * silu_mod(bf2f(bh.x) + bf2f(bl.x));
    yv.y = (bf2f(ah.y) + bf2f(al.y) + sv.y * d) * silu_mod(bf2f(bh.y) + bf2f(bl.y));
    yv.z = (bf2f(ah.z) + bf2f(al.z) + sv.z * d) * silu_mod(bf2f(bh.z) + bf2f(bl.z));
    yv.w = (bf2f(ah.w) + bf2f(al.w) + sv.w * d) * silu_mod(bf2f(bh.w) + bf2f(bl.w));
    ushort4 hv, lv;
    split4(yv, &hv, &lv);
    // packed offset: chunk = ((row/16)*64 + cc/32)*64 + ((cc>>3)&3)*16 + row%16
    size_t chunk = (((size_t)(row >> 4) * 64 + (cc >> 5)) * 64) + ((cc >> 3) & 3) * 16 + (row & 15);
    size_t o = chunk * 8 + (cc & 7);
    *(ushort4*)(yph + o) = hv;
    *(ushort4*)(ypl + o) = lv;
}

// ---------------------------------------------------------------------------
extern "C" void kernel_launch(void* const* d_in, const int* in_sizes, int n_in,
                              void* d_out, int out_size, void* d_ws, size_t ws_size,
                              hipStream_t stream)
{
    const float* u       = (const float*)d_in[0];
    const float* reward  = (const float*)d_in[1];
    const float* in_w    = (const float*)d_in[2];
    const float* in_b    = (const float*)d_in[3];
    const float* conv_w  = (const float*)d_in[4];
    const float* conv_b  = (const float*)d_in[5];
    const float* bw      = (const float*)d_in[6];
    const float* bb      = (const float*)d_in[7];
    const float* dt_bias = (const float*)d_in[8];
    const float* A_log   = (const float*)d_in[9];
    const float* out_w   = (const float*)d_in[10];
    float* out = (float*)d_out;

    char* p = (char*)d_ws;
    const size_t MB32 = (size_t)4096 * 2048 * 2 * 2;  // 33,554,432 B
    // R0: z split, row-major
    unsigned short* zh  = (unsigned short*)p;
    unsigned short* zl  = zh + (size_t)4096 * 2048;
    // R1: xc split row-major -> ypacked split
    unsigned short* xch = (unsigned short*)(p + MB32);
    unsigned short* xcl = xch + (size_t)4096 * 2048;
    unsigned short* yph = xch;
    unsigned short* ypl = xcl;
    // R2: w1packed -> ylocal split -> w2packed
    char* R2 = p + 2 * MB32;
    unsigned short* w1ph = (unsigned short*)R2;
    unsigned short* w1pl = w1ph + (size_t)264 * 32 * 64 * 8;   // 4,325,376
    unsigned short* ylh  = (unsigned short*)R2;
    unsigned short* yll  = ylh + (size_t)4096 * 2048;
    unsigned short* w2ph = (unsigned short*)R2;
    unsigned short* w2pl = w2ph + (size_t)64 * 64 * 64 * 8;    // 2,097,152
    // tail
    char* ps = p + 3 * MB32;
    float* dtraw = (float*)ps;                 ps += (size_t)4096 * 32 * 4;
    float* decay = (float*)ps;                 ps += (size_t)4096 * 32 * 4;
    float* Fb    = (float*)ps;                 ps += (size_t)32 * 64 * 64 * 4;
    float* Eb    = (float*)ps;                 ps += (size_t)32 * 64 * 4;
    float* Sprev = (float*)ps;                 ps += (size_t)32 * 64 * 64 * 4;

    for (int b = 0; b < 4; b++) {
        const float* ub = u + (size_t)b * 4096 * 1024;
        const float* rb = reward + (size_t)b * 4096;
        float* ob = out + (size_t)b * 4096 * 1024;

        // pack in_w -> R2 (264 tiles x 32 kc x 64 lanes)
        pack_split<5, 1><<<2112, 256, 0, stream>>>(in_w, 1024, w1ph, w1pl);
        // 1) in_proj: A = u fp32 direct (in-register split), B = w1 packed
        mfma_gemm<0, 1024><<<dim3(33, 32), 256, 0, stream>>>(
            ub, nullptr, nullptr, w1ph, w1pl, in_b,
            zh, zl, xch, xcl, dtraw, nullptr);
        // 2) conv + local chunk scan (xc -> ylocal in R2)
        scanA<<<2048, 64, 0, stream>>>(xch, xcl, dtraw, rb, conv_w, conv_b,
                                       dt_bias, A_log, bw, bb,
                                       ylh, yll, decay, Fb, Eb);
        // 3) cross-chunk scan
        scanB<<<8, 256, 0, stream>>>(Fb, Eb, Sprev);
        // 4) gate + carried state -> y fragment-packed into R1
        passC<<<8192, 256, 0, stream>>>(ylh, yll, zh, zl, Sprev, decay, yph, ypl);
        // pack out_w -> R2 (ylocal dead; 64 tiles x 64 kc x 64 lanes)
        pack_split<6, 0><<<1024, 256, 0, stream>>>(out_w, 2048, w2ph, w2pl);
        // 5) out_proj: A = y packed, B = w2 packed -> fp32 out
        mfma_gemm<1, 2048><<<dim3(8, 32), 256, 0, stream>>>(
            nullptr, yph, ypl, w2ph, w2pl, nullptr,
            nullptr, nullptr, nullptr, nullptr, nullptr, ob);
    }
}

// Round 5
// 1338.868 us; speedup vs baseline: 1.1799x; 1.1799x over previous
//
#include <hip/hip_runtime.h>
#include <hip/hip_bf16.h>
#include <math.h>

// D_MODEL=1024, D_INNER=2048, NHEADS=32, HEADDIM=64, CHUNK=64, B=4, L=4096
// C == ones collapses the state dim -> scalar scan per (h,p) channel.
// GEMMs: bf16x3 split MFMA (Ah*Bh + Ah*Bl + Al*Bh), fp32-equivalent, LDS-free
// (operands fragment-packed; one coalesced dwordx4 per fragment), XCD-aware
// block swizzle (g&7 -> row band) for L2 residency of the A band.
// z / xc / ylocal are plain fp32 (same bytes as split-bf16, no pack cost).
//
// Workspace: small layout 102.8 MB (round-2-certified). If ws_size >= 128.5MB
// weights are packed ONCE per call into dedicated regions (saves 6 launches
// + ~200MB of traffic); else per-batch into R2 exactly like round 4.

typedef __attribute__((ext_vector_type(8))) short bf16x8;
typedef __attribute__((ext_vector_type(4))) float f32x4;

__device__ __forceinline__ float bf2f(unsigned short u) {
    union { float f; unsigned int i; } x; x.i = ((unsigned int)u) << 16; return x.f;
}
__device__ __forceinline__ unsigned short f2bf(float f) {  // RNE
    union { float f; unsigned int i; } x; x.f = f;
    unsigned int r = x.i + 0x7fffu + ((x.i >> 16) & 1u);
    return (unsigned short)(r >> 16);
}
__device__ __forceinline__ float softplusf(float x) {
    return (x > 20.f) ? x : log1pf(expf(x));
}
__device__ __forceinline__ float silu_mod(float x) {  // sigmoid(x)+0.1x per ref
    return 1.f / (1.f + expf(-x)) + 0.1f * x;
}
// packed split: (x,y) -> hi pair (2xbf16 in uint) + lo pair
__device__ __forceinline__ void cvt_split2(float x, float y,
                                           unsigned int* hi, unsigned int* lo) {
    __hip_bfloat162 h2 = __float22bfloat162_rn(make_float2(x, y));
    unsigned int h; __builtin_memcpy(&h, &h2, 4);
    union { float f; unsigned int i; } fx, fy;
    fx.i = h << 16;
    fy.i = h & 0xffff0000u;
    __hip_bfloat162 l2 = __float22bfloat162_rn(make_float2(x - fx.f, y - fy.f));
    unsigned int l; __builtin_memcpy(&l, &l2, 4);
    *hi = h; *lo = l;
}
__device__ __forceinline__ void split4(float4 v, ushort4* h, ushort4* l) {
    unsigned short t;
    t = f2bf(v.x); h->x = t; l->x = f2bf(v.x - bf2f(t));
    t = f2bf(v.y); h->y = t; l->y = f2bf(v.y - bf2f(t));
    t = f2bf(v.z); h->z = t; l->z = f2bf(v.z - bf2f(t));
    t = f2bf(v.w); h->w = t; l->w = f2bf(v.w - bf2f(t));
}

// ---------------------------------------------------------------------------
// pack weights row-major fp32 -> fragment-order split bf16.
// thread t -> (tile = t>>(6+KCN_LOG), kc = (t>>6)&(KCN-1), lane = t&63):
//   data = src[tile*16 + (lane&15)][kc*32 + (lane>>4)*8 .. +8]
// REMAP (in_w): row<4096 -> row; 4096..4127 -> row+128 (dt cols); else zero.
// ---------------------------------------------------------------------------
template <int KCN_LOG, int REMAP>
__global__ __launch_bounds__(256) void pack_split(
    const float* __restrict__ src, int src_ld,
    unsigned short* __restrict__ h, unsigned short* __restrict__ l)
{
    int t = blockIdx.x * 256 + threadIdx.x;
    int lane = t & 63;
    int kc = (t >> 6) & ((1 << KCN_LOG) - 1);
    int tile = t >> (6 + KCN_LOG);
    int n = tile * 16 + (lane & 15);
    int k = kc * 32 + (lane >> 4) * 8;
    int sr = n;
    if (REMAP) sr = (n < 4096) ? n : (n < 4128 ? n + 128 : -1);
    float4 v0 = make_float4(0.f, 0.f, 0.f, 0.f), v1 = v0;
    if (sr >= 0) {
        const float* s = src + (size_t)sr * src_ld + k;
        v0 = *(const float4*)s;
        v1 = *(const float4*)(s + 4);
    }
    ushort4 h0, l0, h1, l1;
    split4(v0, &h0, &l0);
    split4(v1, &h1, &l1);
    size_t o = (size_t)t * 8;
    *(ushort4*)(h + o) = h0; *(ushort4*)(h + o + 4) = h1;
    *(ushort4*)(l + o) = l0; *(ushort4*)(l + o + 4) = l1;
}

// ---------------------------------------------------------------------------
// LDS-free bf16x3 MFMA NT-GEMM, XCD-swizzled 1D grid:
//   g -> xcd=g&7, j=g>>3: m-block = xcd*4 + (j&3), n-block = j>>2.
// Each XCD owns a 4-row band (2MB A working set, L2-resident) and streams B.
// 128x128 block, 4 waves (2x2), wave does 4x4 tiles of 16x16x32.
// MODE 0: A = fp32 row-major (direct loads + in-register split);
//         fp32 stores z / xc / dtraw.
// MODE 1: A = fragment-packed split bf16; fp32 out.
// ---------------------------------------------------------------------------
template <int MODE, int KDIM>
__global__ __launch_bounds__(256, 2) void mfma_gemm(
    const float* __restrict__ Af,
    const unsigned short* __restrict__ Aph, const unsigned short* __restrict__ Apl,
    const unsigned short* __restrict__ Bph, const unsigned short* __restrict__ Bpl,
    const float* __restrict__ bias,
    float* __restrict__ oz, float* __restrict__ oxc,
    float* __restrict__ dtraw, float* __restrict__ outC)
{
    constexpr int KCN = KDIM / 32;
    const int g = blockIdx.x;
    const int m0 = ((g & 7) * 4 + ((g >> 3) & 3)) * 128;
    const int n0 = (g >> 5) * 128;
    const int tid = threadIdx.x;
    const int lane = tid & 63, w = tid >> 6;
    const int wm = w & 1, wn = w >> 1;
    const int fr = lane & 15, q = lane >> 4;

    // B fragment pointers (advance 512 shorts per k-step)
    const unsigned short* bhp[4];
    const unsigned short* blp[4];
#pragma unroll
    for (int nt = 0; nt < 4; nt++) {
        size_t c = ((size_t)((n0 >> 4) + wn * 4 + nt) * KCN * 64 + lane) * 8;
        bhp[nt] = Bph + c;
        blp[nt] = Bpl + c;
    }
    // A pointers
    const float* afp[4];
    const unsigned short* ahp[4];
    const unsigned short* alp[4];
#pragma unroll
    for (int mt = 0; mt < 4; mt++) {
        if (MODE == 0) {
            afp[mt] = Af + (size_t)(m0 + wm * 64 + mt * 16 + fr) * KDIM + q * 8;
        } else {
            size_t c = ((size_t)((m0 >> 4) + wm * 4 + mt) * KCN * 64 + lane) * 8;
            ahp[mt] = Aph + c;
            alp[mt] = Apl + c;
        }
    }

    f32x4 acc[4][4];
#pragma unroll
    for (int i = 0; i < 4; i++)
#pragma unroll
        for (int j = 0; j < 4; j++) acc[i][j] = (f32x4){0.f, 0.f, 0.f, 0.f};

#pragma unroll 2
    for (int kc = 0; kc < KCN; kc++) {
        bf16x8 a_h[4], a_l[4], b_h[4], b_l[4];
#pragma unroll
        for (int nt = 0; nt < 4; nt++) {
            b_h[nt] = *(const bf16x8*)bhp[nt];
            b_l[nt] = *(const bf16x8*)blp[nt];
            bhp[nt] += 512;
            blp[nt] += 512;
        }
#pragma unroll
        for (int mt = 0; mt < 4; mt++) {
            if (MODE == 0) {
                float4 a0 = *(const float4*)afp[mt];
                float4 a1 = *(const float4*)(afp[mt] + 4);
                afp[mt] += 32;
                union { bf16x8 v; unsigned int u[4]; } H, L;
                cvt_split2(a0.x, a0.y, &H.u[0], &L.u[0]);
                cvt_split2(a0.z, a0.w, &H.u[1], &L.u[1]);
                cvt_split2(a1.x, a1.y, &H.u[2], &L.u[2]);
                cvt_split2(a1.z, a1.w, &H.u[3], &L.u[3]);
                a_h[mt] = H.v; a_l[mt] = L.v;
            } else {
                a_h[mt] = *(const bf16x8*)ahp[mt];
                a_l[mt] = *(const bf16x8*)alp[mt];
                ahp[mt] += 512;
                alp[mt] += 512;
            }
        }
#pragma unroll
        for (int mt = 0; mt < 4; mt++)
#pragma unroll
            for (int nt = 0; nt < 4; nt++) {
                acc[mt][nt] = __builtin_amdgcn_mfma_f32_16x16x32_bf16(
                    a_h[mt], b_h[nt], acc[mt][nt], 0, 0, 0);
                acc[mt][nt] = __builtin_amdgcn_mfma_f32_16x16x32_bf16(
                    a_h[mt], b_l[nt], acc[mt][nt], 0, 0, 0);
                acc[mt][nt] = __builtin_amdgcn_mfma_f32_16x16x32_bf16(
                    a_l[mt], b_h[nt], acc[mt][nt], 0, 0, 0);
            }
    }

    // epilogue: D[row=q*4+reg][col=fr] per 16x16 tile; fp32 stores (64B/quarter)
#pragma unroll
    for (int nt = 0; nt < 4; nt++) {
        int jn = n0 + wn * 64 + nt * 16 + fr;
        if (MODE == 0 && jn >= 4128) continue;
        float bv = 0.f;
        if (MODE == 0) bv = bias[jn < 4096 ? jn : jn + 128];
#pragma unroll
        for (int mt = 0; mt < 4; mt++) {
#pragma unroll
            for (int reg = 0; reg < 4; reg++) {
                int rm = m0 + wm * 64 + mt * 16 + q * 4 + reg;
                float v = acc[mt][nt][reg] + bv;
                if (MODE == 0) {
                    if (jn < 2048)      oz[(size_t)rm * 2048 + jn] = v;
                    else if (jn < 4096) oxc[(size_t)rm * 2048 + (jn - 2048)] = v;
                    else                dtraw[(size_t)rm * 32 + (jn - 4096)] = v;
                } else {
                    outC[(size_t)rm * 1024 + jn] = v;
                }
            }
        }
    }
}

// ---------------------------------------------------------------------------
// scanA: one batch. Per (h, chunk) block, 64 threads (p). conv4 + silu' +
// softplus(dt) + decay cumsum + 64-step local scan. xc/ylocal fp32.
// ---------------------------------------------------------------------------
__global__ __launch_bounds__(64) void scanA(
    const float* __restrict__ xc,
    const float* __restrict__ dtraw, const float* __restrict__ reward,
    const float* __restrict__ conv_w, const float* __restrict__ conv_b,
    const float* __restrict__ dt_bias, const float* __restrict__ A_log,
    const float* __restrict__ bw, const float* __restrict__ bb,
    float* __restrict__ ylocal,
    float* __restrict__ decay, float* __restrict__ Fb, float* __restrict__ Eb)
{
    const int blk = blockIdx.x;        // h*64 + t
    const int t = blk & 63;
    const int h = blk >> 6;
    const int p = threadIdx.x;
    const int l0 = t * 64;

    __shared__ float xs[67][65];
    __shared__ float gbuf[64], ebuf[64], dtbuf[64];
    __shared__ float cum63;

    float v1 = bw[p] + bw[p + 64];
    float v2 = bb[p] + bb[p + 64];
#pragma unroll
    for (int o = 32; o > 0; o >>= 1) {
        v1 += __shfl_down(v1, o, 64);
        v2 += __shfl_down(v2, o, 64);
    }
    const float sbw = __shfl(v1, 0, 64);
    const float sbb = __shfl(v2, 0, 64);

    const int l = l0 + p;
    const float dt = softplusf(dtraw[(size_t)l * 32 + h] + dt_bias[h]);
    const float a = -expf(A_log[h]) * dt;
    float cum = a;
#pragma unroll
    for (int o = 1; o < 64; o <<= 1) {
        float uo = __shfl_up(cum, o, 64);
        if (p >= o) cum += uo;
    }
    decay[(size_t)l * 32 + h] = expf(cum);
    gbuf[p] = reward[l] * sbw + sbb;
    ebuf[p] = expf(a);
    dtbuf[p] = dt;
    if (p == 63) cum63 = cum;

    const int c = h * 64 + p;
    for (int r = 0; r < 67; r++) {
        int ls = l0 - 3 + r;
        xs[r][p] = (ls >= 0) ? xc[(size_t)ls * 2048 + c] : 0.f;
    }
    __syncthreads();

    const float w0 = conv_w[c * 4 + 0], w1 = conv_w[c * 4 + 1],
                w2 = conv_w[c * 4 + 2], w3 = conv_w[c * 4 + 3];
    const float cb = conv_b[c];
    float y = 0.f;
    float* outp = ylocal + (size_t)l0 * 2048 + c;
#pragma unroll 4
    for (int i = 0; i < 64; i++) {
        float v = cb + xs[i][p] * w0 + xs[i + 1][p] * w1 +
                  xs[i + 2][p] * w2 + xs[i + 3][p] * w3;
        float xdt = silu_mod(v) * dtbuf[i];
        y = y * ebuf[i] + gbuf[i] * xdt;
        outp[(size_t)i * 2048] = y;
    }
    Fb[((size_t)h * 64 + t) * 64 + p] = y;
    if (p == 0) Eb[(size_t)h * 64 + t] = expf(cum63);
}

// ---------------------------------------------------------------------------
__global__ void scanB(const float* __restrict__ Fb, const float* __restrict__ Eb,
                      float* __restrict__ Sprev)
{
    int idx = blockIdx.x * blockDim.x + threadIdx.x;  // 2048
    int p = idx & 63;
    int h = idx >> 6;
    int base = h * 64;
    float S = 0.f;
    for (int t = 0; t < 64; t++) {
        Sprev[(size_t)(base + t) * 64 + p] = S;
        S = S * Eb[base + t] + Fb[(size_t)(base + t) * 64 + p];
    }
}

// ---------------------------------------------------------------------------
// passC: y = (ylocal + S*decay) * silu_mod(z), emitted split bf16 directly in
// gemm2's A fragment-packed order (KCN=64).
// ---------------------------------------------------------------------------
__global__ __launch_bounds__(256) void passC(
    const float* __restrict__ yl, const float* __restrict__ z,
    const float* __restrict__ Sprev, const float* __restrict__ decay,
    unsigned short* __restrict__ yph, unsigned short* __restrict__ ypl)
{
    size_t idx = ((size_t)blockIdx.x * 256 + threadIdx.x) * 4;
    int row = (int)(idx >> 11);
    int cc = (int)(idx & 2047);
    int t = row >> 6;
    int h = cc >> 6, p = cc & 63;
    float4 av = *(const float4*)(yl + idx);
    float4 bvz = *(const float4*)(z + idx);
    float4 sv = *(const float4*)(Sprev + ((size_t)(h * 64 + t)) * 64 + p);
    float d = decay[(size_t)row * 32 + h];
    float4 yv;
    yv.x = (av.x + sv.x * d) * silu_mod(bvz.x);
    yv.y = (av.y + sv.y * d) * silu_mod(bvz.y);
    yv.z = (av.z + sv.z * d) * silu_mod(bvz.z);
    yv.w = (av.w + sv.w * d) * silu_mod(bvz.w);
    ushort4 hv, lv;
    split4(yv, &hv, &lv);
    // packed offset: chunk = ((row/16)*64 + cc/32)*64 + ((cc>>3)&3)*16 + row%16
    size_t chunk = (((size_t)(row >> 4) * 64 + (cc >> 5)) * 64) + ((cc >> 3) & 3) * 16 + (row & 15);
    size_t o = chunk * 8 + (cc & 7);
    *(ushort4*)(yph + o) = hv;
    *(ushort4*)(ypl + o) = lv;
}

// ---------------------------------------------------------------------------
extern "C" void kernel_launch(void* const* d_in, const int* in_sizes, int n_in,
                              void* d_out, int out_size, void* d_ws, size_t ws_size,
                              hipStream_t stream)
{
    const float* u       = (const float*)d_in[0];
    const float* reward  = (const float*)d_in[1];
    const float* in_w    = (const float*)d_in[2];
    const float* in_b    = (const float*)d_in[3];
    const float* conv_w  = (const float*)d_in[4];
    const float* conv_b  = (const float*)d_in[5];
    const float* bw      = (const float*)d_in[6];
    const float* bb      = (const float*)d_in[7];
    const float* dt_bias = (const float*)d_in[8];
    const float* A_log   = (const float*)d_in[9];
    const float* out_w   = (const float*)d_in[10];
    float* out = (float*)d_out;

    char* p = (char*)d_ws;
    const size_t SEG = (size_t)4096 * 2048 * 4;  // 33,554,432 B
    // R0: z fp32
    float* z = (float*)p;
    // R1: xc fp32 -> ypacked split bf16
    float* xc = (float*)(p + SEG);
    unsigned short* yph = (unsigned short*)(p + SEG);
    unsigned short* ypl = yph + (size_t)4096 * 2048;
    // R2: (small layout: w1p -> ) ylocal fp32 ( -> w2p)
    char* R2 = p + 2 * SEG;
    float* ylocal = (float*)R2;
    // tail
    char* ps = p + 3 * SEG;
    float* dtraw = (float*)ps;                 ps += (size_t)4096 * 32 * 4;
    float* decay = (float*)ps;                 ps += (size_t)4096 * 32 * 4;
    float* Fb    = (float*)ps;                 ps += (size_t)32 * 64 * 64 * 4;
    float* Eb    = (float*)ps;                 ps += (size_t)32 * 64 * 4;
    float* Sprev = (float*)ps;                 ps += (size_t)32 * 64 * 64 * 4;

    const size_t W1PN = (size_t)264 * 32 * 64 * 8;  // shorts per w1 half
    const size_t W2PN = (size_t)64 * 64 * 64 * 8;   // shorts per w2 half
    size_t used_small = (size_t)(ps - (char*)d_ws);
    bool big = ws_size >= used_small + (W1PN + W2PN) * 2 * sizeof(unsigned short);

    unsigned short *w1ph, *w1pl, *w2ph, *w2pl;
    if (big) {
        w1ph = (unsigned short*)ps;
        w1pl = w1ph + W1PN;
        w2ph = w1pl + W1PN;
        w2pl = w2ph + W2PN;
        // pack once per call
        pack_split<5, 1><<<2112, 256, 0, stream>>>(in_w, 1024, w1ph, w1pl);
        pack_split<6, 0><<<1024, 256, 0, stream>>>(out_w, 2048, w2ph, w2pl);
    } else {
        w1ph = (unsigned short*)R2;
        w1pl = w1ph + W1PN;
        w2ph = (unsigned short*)R2;
        w2pl = w2ph + W2PN;
    }

    for (int b = 0; b < 4; b++) {
        const float* ub = u + (size_t)b * 4096 * 1024;
        const float* rb = reward + (size_t)b * 4096;
        float* ob = out + (size_t)b * 4096 * 1024;

        if (!big)  // pack in_w into R2 (recycled below)
            pack_split<5, 1><<<2112, 256, 0, stream>>>(in_w, 1024, w1ph, w1pl);
        // 1) in_proj: A = u fp32 direct (in-register split), B = w1 packed
        //    grid 33*4*8: xcd-swizzled
        mfma_gemm<0, 1024><<<1056, 256, 0, stream>>>(
            ub, nullptr, nullptr, w1ph, w1pl, in_b,
            z, xc, dtraw, nullptr);
        // 2) conv + local chunk scan (xc -> ylocal in R2)
        scanA<<<2048, 64, 0, stream>>>(xc, dtraw, rb, conv_w, conv_b,
                                       dt_bias, A_log, bw, bb,
                                       ylocal, decay, Fb, Eb);
        // 3) cross-chunk scan
        scanB<<<8, 256, 0, stream>>>(Fb, Eb, Sprev);
        // 4) gate + carried state -> y fragment-packed into R1
        passC<<<8192, 256, 0, stream>>>(ylocal, z, Sprev, decay, yph, ypl);
        if (!big)  // pack out_w into R2 (ylocal dead after passC)
            pack_split<6, 0><<<1024, 256, 0, stream>>>(out_w, 2048, w2ph, w2pl);
        // 5) out_proj: A = y packed, B = w2 packed -> fp32 out; grid 8*4*8
        mfma_gemm<1, 2048><<<256, 256, 0, stream>>>(
            nullptr, yph, ypl, w2ph, w2pl, nullptr,
            nullptr, nullptr, nullptr, ob);
    }
}

// Round 6
// 1258.284 us; speedup vs baseline: 1.2554x; 1.0640x over previous
//
#include <hip/hip_runtime.h>
#include <hip/hip_bf16.h>
#include <math.h>

// D_MODEL=1024, D_INNER=2048, NHEADS=32, HEADDIM=64, CHUNK=64, B=4, L=4096
// C == ones collapses the state dim -> scalar scan per (h,p) channel.
// GEMMs: bf16x3 split MFMA (Ah*Bh + Ah*Bl + Al*Bh), fp32-equivalent, LDS-free
// (fragment-packed operands, 1 coalesced dwordx4 per fragment), XCD swizzle,
// and an explicit 2-stage register double-buffer in the K-loop (no barriers).
//
// ws tiers (runtime-checked, deterministic):
//  small  ~100.3 MB : round-5 layout, weights packed per batch, A split in-reg
//  +25.7  ~126.0 MB : weights packed once per call
//  +16.8  ~142.8 MB : u fragment-packed per batch -> GEMM1 K-loop is pure MFMA

typedef __attribute__((ext_vector_type(8))) short bf16x8;
typedef __attribute__((ext_vector_type(4))) float f32x4;

__device__ __forceinline__ float bf2f(unsigned short u) {
    union { float f; unsigned int i; } x; x.i = ((unsigned int)u) << 16; return x.f;
}
__device__ __forceinline__ unsigned short f2bf(float f) {  // RNE
    union { float f; unsigned int i; } x; x.f = f;
    unsigned int r = x.i + 0x7fffu + ((x.i >> 16) & 1u);
    return (unsigned short)(r >> 16);
}
__device__ __forceinline__ float softplusf(float x) {
    return (x > 20.f) ? x : log1pf(expf(x));
}
__device__ __forceinline__ float silu_mod(float x) {  // sigmoid(x)+0.1x per ref
    return 1.f / (1.f + expf(-x)) + 0.1f * x;
}
__device__ __forceinline__ void cvt_split2(float x, float y,
                                           unsigned int* hi, unsigned int* lo) {
    __hip_bfloat162 h2 = __float22bfloat162_rn(make_float2(x, y));
    unsigned int h; __builtin_memcpy(&h, &h2, 4);
    union { float f; unsigned int i; } fx, fy;
    fx.i = h << 16;
    fy.i = h & 0xffff0000u;
    __hip_bfloat162 l2 = __float22bfloat162_rn(make_float2(x - fx.f, y - fy.f));
    unsigned int l; __builtin_memcpy(&l, &l2, 4);
    *hi = h; *lo = l;
}
__device__ __forceinline__ void split4(float4 v, ushort4* h, ushort4* l) {
    unsigned short t;
    t = f2bf(v.x); h->x = t; l->x = f2bf(v.x - bf2f(t));
    t = f2bf(v.y); h->y = t; l->y = f2bf(v.y - bf2f(t));
    t = f2bf(v.z); h->z = t; l->z = f2bf(v.z - bf2f(t));
    t = f2bf(v.w); h->w = t; l->w = f2bf(v.w - bf2f(t));
}

// ---------------------------------------------------------------------------
// pack row-major fp32 -> fragment-order split bf16.
// thread t -> (tile = t>>(6+KCN_LOG), kc = (t>>6)&(KCN-1), lane = t&63):
//   data = src[tile*16 + (lane&15)][kc*32 + (lane>>4)*8 .. +8]
// REMAP (in_w): row<4096 -> row; 4096..4127 -> row+128 (dt cols); else zero.
// ---------------------------------------------------------------------------
template <int KCN_LOG, int REMAP>
__global__ __launch_bounds__(256) void pack_split(
    const float* __restrict__ src, int src_ld,
    unsigned short* __restrict__ h, unsigned short* __restrict__ l)
{
    int t = blockIdx.x * 256 + threadIdx.x;
    int lane = t & 63;
    int kc = (t >> 6) & ((1 << KCN_LOG) - 1);
    int tile = t >> (6 + KCN_LOG);
    int n = tile * 16 + (lane & 15);
    int k = kc * 32 + (lane >> 4) * 8;
    int sr = n;
    if (REMAP) sr = (n < 4096) ? n : (n < 4128 ? n + 128 : -1);
    float4 v0 = make_float4(0.f, 0.f, 0.f, 0.f), v1 = v0;
    if (sr >= 0) {
        const float* s = src + (size_t)sr * src_ld + k;
        v0 = *(const float4*)s;
        v1 = *(const float4*)(s + 4);
    }
    ushort4 h0, l0, h1, l1;
    split4(v0, &h0, &l0);
    split4(v1, &h1, &l1);
    size_t o = (size_t)t * 8;
    *(ushort4*)(h + o) = h0; *(ushort4*)(h + o + 4) = h1;
    *(ushort4*)(l + o) = l0; *(ushort4*)(l + o + 4) = l1;
}

// ---------------------------------------------------------------------------
// LDS-free bf16x3 MFMA NT-GEMM, XCD-swizzled 1D grid:
//   g -> xcd=g&7, m-block = xcd*4 + ((g>>3)&3), n-block = g>>5.
// 128x128 block, 4 waves (2x2), wave = 4x4 tiles of 16x16x32.
// Explicit 2-stage register double-buffer K-loop (prefetch k+1 over MFMA k).
// ASRC 0: A fp32 row-major, split in-register.  ASRC 1: A fragment-packed.
// OUT  0: fp32 stores z / xc / dtraw (in_proj).  OUT 1: fp32 C (out_proj).
// ---------------------------------------------------------------------------
template <int ASRC, int OUT, int KDIM>
__global__ __launch_bounds__(256, 2) void mfma_gemm(
    const float* __restrict__ Af,
    const unsigned short* __restrict__ Aph, const unsigned short* __restrict__ Apl,
    const unsigned short* __restrict__ Bph, const unsigned short* __restrict__ Bpl,
    const float* __restrict__ bias,
    float* __restrict__ oz, float* __restrict__ oxc,
    float* __restrict__ dtraw, float* __restrict__ outC)
{
    constexpr int KCN = KDIM / 32;
    const int g = blockIdx.x;
    const int m0 = ((g & 7) * 4 + ((g >> 3) & 3)) * 128;
    const int n0 = (g >> 5) * 128;
    const int tid = threadIdx.x;
    const int lane = tid & 63, w = tid >> 6;
    const int wm = w & 1, wn = w >> 1;
    const int fr = lane & 15, q = lane >> 4;

    const unsigned short* bhp[4];
    const unsigned short* blp[4];
#pragma unroll
    for (int nt = 0; nt < 4; nt++) {
        size_t c = ((size_t)((n0 >> 4) + wn * 4 + nt) * KCN * 64 + lane) * 8;
        bhp[nt] = Bph + c;
        blp[nt] = Bpl + c;
    }
    const float* afp[4];
    const unsigned short* ahp[4];
    const unsigned short* alp[4];
#pragma unroll
    for (int mt = 0; mt < 4; mt++) {
        if (ASRC == 0) {
            afp[mt] = Af + (size_t)(m0 + wm * 64 + mt * 16 + fr) * KDIM + q * 8;
        } else {
            size_t c = ((size_t)((m0 >> 4) + wm * 4 + mt) * KCN * 64 + lane) * 8;
            ahp[mt] = Aph + c;
            alp[mt] = Apl + c;
        }
    }

    f32x4 acc[4][4];
#pragma unroll
    for (int i = 0; i < 4; i++)
#pragma unroll
        for (int j = 0; j < 4; j++) acc[i][j] = (f32x4){0.f, 0.f, 0.f, 0.f};

    bf16x8 bh[2][4], bl[2][4], ah[2][4], al[2][4];
    float4 af0[2][4], af1[2][4];

#define LOAD_STEP(B)                                                          \
    {                                                                         \
        _Pragma("unroll") for (int nt = 0; nt < 4; nt++) {                    \
            bh[B][nt] = *(const bf16x8*)bhp[nt];                              \
            bl[B][nt] = *(const bf16x8*)blp[nt];                              \
            bhp[nt] += 512; blp[nt] += 512;                                   \
        }                                                                     \
        _Pragma("unroll") for (int mt = 0; mt < 4; mt++) {                    \
            if (ASRC == 1) {                                                  \
                ah[B][mt] = *(const bf16x8*)ahp[mt];                          \
                al[B][mt] = *(const bf16x8*)alp[mt];                          \
                ahp[mt] += 512; alp[mt] += 512;                               \
            } else {                                                          \
                af0[B][mt] = *(const float4*)afp[mt];                         \
                af1[B][mt] = *(const float4*)(afp[mt] + 4);                   \
                afp[mt] += 32;                                                \
            }                                                                 \
        }                                                                     \
    }

#define MFMA_STEP(B)                                                          \
    {                                                                         \
        bf16x8 xah[4], xal[4];                                                \
        _Pragma("unroll") for (int mt = 0; mt < 4; mt++) {                    \
            if (ASRC == 1) {                                                  \
                xah[mt] = ah[B][mt]; xal[mt] = al[B][mt];                     \
            } else {                                                          \
                union { bf16x8 v; unsigned int u[4]; } H, L;                  \
                cvt_split2(af0[B][mt].x, af0[B][mt].y, &H.u[0], &L.u[0]);     \
                cvt_split2(af0[B][mt].z, af0[B][mt].w, &H.u[1], &L.u[1]);     \
                cvt_split2(af1[B][mt].x, af1[B][mt].y, &H.u[2], &L.u[2]);     \
                cvt_split2(af1[B][mt].z, af1[B][mt].w, &H.u[3], &L.u[3]);     \
                xah[mt] = H.v; xal[mt] = L.v;                                 \
            }                                                                 \
        }                                                                     \
        _Pragma("unroll") for (int mt = 0; mt < 4; mt++)                      \
            _Pragma("unroll") for (int nt = 0; nt < 4; nt++)                  \
                acc[mt][nt] = __builtin_amdgcn_mfma_f32_16x16x32_bf16(        \
                    xah[mt], bh[B][nt], acc[mt][nt], 0, 0, 0);                \
        _Pragma("unroll") for (int mt = 0; mt < 4; mt++)                      \
            _Pragma("unroll") for (int nt = 0; nt < 4; nt++)                  \
                acc[mt][nt] = __builtin_amdgcn_mfma_f32_16x16x32_bf16(        \
                    xah[mt], bl[B][nt], acc[mt][nt], 0, 0, 0);                \
        _Pragma("unroll") for (int mt = 0; mt < 4; mt++)                      \
            _Pragma("unroll") for (int nt = 0; nt < 4; nt++)                  \
                acc[mt][nt] = __builtin_amdgcn_mfma_f32_16x16x32_bf16(        \
                    xal[mt], bh[B][nt], acc[mt][nt], 0, 0, 0);                \
    }

    LOAD_STEP(0);
    for (int kc = 0; kc + 2 < KCN; kc += 2) {
        LOAD_STEP(1);
        MFMA_STEP(0);
        LOAD_STEP(0);
        MFMA_STEP(1);
    }
    LOAD_STEP(1);
    MFMA_STEP(0);
    MFMA_STEP(1);
#undef LOAD_STEP
#undef MFMA_STEP

    // epilogue: D[row=q*4+reg][col=fr] per 16x16 tile
#pragma unroll
    for (int nt = 0; nt < 4; nt++) {
        int jn = n0 + wn * 64 + nt * 16 + fr;
        if (OUT == 0 && jn >= 4128) continue;
        float bv = 0.f;
        if (OUT == 0) bv = bias[jn < 4096 ? jn : jn + 128];
#pragma unroll
        for (int mt = 0; mt < 4; mt++) {
#pragma unroll
            for (int reg = 0; reg < 4; reg++) {
                int rm = m0 + wm * 64 + mt * 16 + q * 4 + reg;
                float v = acc[mt][nt][reg] + bv;
                if (OUT == 0) {
                    if (jn < 2048)      oz[(size_t)rm * 2048 + jn] = v;
                    else if (jn < 4096) oxc[(size_t)rm * 2048 + (jn - 2048)] = v;
                    else                dtraw[(size_t)rm * 32 + (jn - 4096)] = v;
                } else {
                    outC[(size_t)rm * 1024 + jn] = v;
                }
            }
        }
    }
}

// ---------------------------------------------------------------------------
// scanA: one batch. Per (h, chunk) block, 64 threads (p). conv4 + silu' +
// softplus(dt) + decay cumsum + 64-step local scan. xc/ylocal fp32.
// ---------------------------------------------------------------------------
__global__ __launch_bounds__(64) void scanA(
    const float* __restrict__ xc,
    const float* __restrict__ dtraw, const float* __restrict__ reward,
    const float* __restrict__ conv_w, const float* __restrict__ conv_b,
    const float* __restrict__ dt_bias, const float* __restrict__ A_log,
    const float* __restrict__ bw, const float* __restrict__ bb,
    float* __restrict__ ylocal,
    float* __restrict__ decay, float* __restrict__ Fb, float* __restrict__ Eb)
{
    const int blk = blockIdx.x;        // h*64 + t
    const int t = blk & 63;
    const int h = blk >> 6;
    const int p = threadIdx.x;
    const int l0 = t * 64;

    __shared__ float xs[67][65];
    __shared__ float gbuf[64], ebuf[64], dtbuf[64];
    __shared__ float cum63;

    float v1 = bw[p] + bw[p + 64];
    float v2 = bb[p] + bb[p + 64];
#pragma unroll
    for (int o = 32; o > 0; o >>= 1) {
        v1 += __shfl_down(v1, o, 64);
        v2 += __shfl_down(v2, o, 64);
    }
    const float sbw = __shfl(v1, 0, 64);
    const float sbb = __shfl(v2, 0, 64);

    const int l = l0 + p;
    const float dt = softplusf(dtraw[(size_t)l * 32 + h] + dt_bias[h]);
    const float a = -expf(A_log[h]) * dt;
    float cum = a;
#pragma unroll
    for (int o = 1; o < 64; o <<= 1) {
        float uo = __shfl_up(cum, o, 64);
        if (p >= o) cum += uo;
    }
    decay[(size_t)l * 32 + h] = expf(cum);
    gbuf[p] = reward[l] * sbw + sbb;
    ebuf[p] = expf(a);
    dtbuf[p] = dt;
    if (p == 63) cum63 = cum;

    const int c = h * 64 + p;
    for (int r = 0; r < 67; r++) {
        int ls = l0 - 3 + r;
        xs[r][p] = (ls >= 0) ? xc[(size_t)ls * 2048 + c] : 0.f;
    }
    __syncthreads();

    const float w0 = conv_w[c * 4 + 0], w1 = conv_w[c * 4 + 1],
                w2 = conv_w[c * 4 + 2], w3 = conv_w[c * 4 + 3];
    const float cb = conv_b[c];
    float y = 0.f;
    float* outp = ylocal + (size_t)l0 * 2048 + c;
#pragma unroll 4
    for (int i = 0; i < 64; i++) {
        float v = cb + xs[i][p] * w0 + xs[i + 1][p] * w1 +
                  xs[i + 2][p] * w2 + xs[i + 3][p] * w3;
        float xdt = silu_mod(v) * dtbuf[i];
        y = y * ebuf[i] + gbuf[i] * xdt;
        outp[(size_t)i * 2048] = y;
    }
    Fb[((size_t)h * 64 + t) * 64 + p] = y;
    if (p == 0) Eb[(size_t)h * 64 + t] = expf(cum63);
}

// ---------------------------------------------------------------------------
__global__ void scanB(const float* __restrict__ Fb, const float* __restrict__ Eb,
                      float* __restrict__ Sprev)
{
    int idx = blockIdx.x * blockDim.x + threadIdx.x;  // 2048
    int p = idx & 63;
    int h = idx >> 6;
    int base = h * 64;
    float S = 0.f;
    for (int t = 0; t < 64; t++) {
        Sprev[(size_t)(base + t) * 64 + p] = S;
        S = S * Eb[base + t] + Fb[(size_t)(base + t) * 64 + p];
    }
}

// ---------------------------------------------------------------------------
// passC: y = (ylocal + S*decay) * silu_mod(z), emitted split bf16 directly in
// gemm2's A fragment-packed order (KCN=64).
// ---------------------------------------------------------------------------
__global__ __launch_bounds__(256) void passC(
    const float* __restrict__ yl, const float* __restrict__ z,
    const float* __restrict__ Sprev, const float* __restrict__ decay,
    unsigned short* __restrict__ yph, unsigned short* __restrict__ ypl)
{
    size_t idx = ((size_t)blockIdx.x * 256 + threadIdx.x) * 4;
    int row = (int)(idx >> 11);
    int cc = (int)(idx & 2047);
    int t = row >> 6;
    int h = cc >> 6, p = cc & 63;
    float4 av = *(const float4*)(yl + idx);
    float4 bvz = *(const float4*)(z + idx);
    float4 sv = *(const float4*)(Sprev + ((size_t)(h * 64 + t)) * 64 + p);
    float d = decay[(size_t)row * 32 + h];
    float4 yv;
    yv.x = (av.x + sv.x * d) * silu_mod(bvz.x);
    yv.y = (av.y + sv.y * d) * silu_mod(bvz.y);
    yv.z = (av.z + sv.z * d) * silu_mod(bvz.z);
    yv.w = (av.w + sv.w * d) * silu_mod(bvz.w);
    ushort4 hv, lv;
    split4(yv, &hv, &lv);
    size_t chunk = (((size_t)(row >> 4) * 64 + (cc >> 5)) * 64) + ((cc >> 3) & 3) * 16 + (row & 15);
    size_t o = chunk * 8 + (cc & 7);
    *(ushort4*)(yph + o) = hv;
    *(ushort4*)(ypl + o) = lv;
}

// ---------------------------------------------------------------------------
extern "C" void kernel_launch(void* const* d_in, const int* in_sizes, int n_in,
                              void* d_out, int out_size, void* d_ws, size_t ws_size,
                              hipStream_t stream)
{
    const float* u       = (const float*)d_in[0];
    const float* reward  = (const float*)d_in[1];
    const float* in_w    = (const float*)d_in[2];
    const float* in_b    = (const float*)d_in[3];
    const float* conv_w  = (const float*)d_in[4];
    const float* conv_b  = (const float*)d_in[5];
    const float* bw      = (const float*)d_in[6];
    const float* bb      = (const float*)d_in[7];
    const float* dt_bias = (const float*)d_in[8];
    const float* A_log   = (const float*)d_in[9];
    const float* out_w   = (const float*)d_in[10];
    float* out = (float*)d_out;

    char* p = (char*)d_ws;
    const size_t SEG = (size_t)4096 * 2048 * 4;  // 33,554,432 B
    float* z = (float*)p;                              // R0
    float* xc = (float*)(p + SEG);                     // R1 (-> ypacked)
    unsigned short* yph = (unsigned short*)(p + SEG);
    unsigned short* ypl = yph + (size_t)4096 * 2048;
    char* R2 = p + 2 * SEG;                            // R2
    float* ylocal = (float*)R2;
    char* ps = p + 3 * SEG;                            // tail
    float* dtraw = (float*)ps;                 ps += (size_t)4096 * 32 * 4;
    float* decay = (float*)ps;                 ps += (size_t)4096 * 32 * 4;
    float* Fb    = (float*)ps;                 ps += (size_t)32 * 64 * 64 * 4;
    float* Eb    = (float*)ps;                 ps += (size_t)32 * 64 * 4;
    float* Sprev = (float*)ps;                 ps += (size_t)32 * 64 * 64 * 4;

    const size_t W1PN = (size_t)264 * 32 * 64 * 8;  // shorts per w1 half
    const size_t W2PN = (size_t)64 * 64 * 64 * 8;   // shorts per w2 half
    const size_t UPN  = (size_t)256 * 32 * 64 * 8;  // shorts per u half
    size_t used_small = (size_t)(ps - (char*)d_ws);
    bool wonce = ws_size >= used_small + 2 * sizeof(unsigned short) * (W1PN + W2PN);
    bool upack = ws_size >= used_small + 2 * sizeof(unsigned short) * (W1PN + W2PN + UPN);

    unsigned short *w1ph, *w1pl, *w2ph, *w2pl, *uph = nullptr, *upl = nullptr;
    if (wonce) {
        w1ph = (unsigned short*)ps;
        w1pl = w1ph + W1PN;
        w2ph = w1pl + W1PN;
        w2pl = w2ph + W2PN;
        pack_split<5, 1><<<2112, 256, 0, stream>>>(in_w, 1024, w1ph, w1pl);
        pack_split<6, 0><<<1024, 256, 0, stream>>>(out_w, 2048, w2ph, w2pl);
        if (upack) {
            uph = w2pl + W2PN;
            upl = uph + UPN;
        }
    } else {
        w1ph = (unsigned short*)R2;
        w1pl = w1ph + W1PN;
        w2ph = (unsigned short*)R2;
        w2pl = w2ph + W2PN;
    }

    for (int b = 0; b < 4; b++) {
        const float* ub = u + (size_t)b * 4096 * 1024;
        const float* rb = reward + (size_t)b * 4096;
        float* ob = out + (size_t)b * 4096 * 1024;

        if (!wonce)
            pack_split<5, 1><<<2112, 256, 0, stream>>>(in_w, 1024, w1ph, w1pl);
        // 1) in_proj (grid 33*4*8, xcd-swizzled)
        if (upack) {
            pack_split<5, 0><<<2048, 256, 0, stream>>>(ub, 1024, uph, upl);
            mfma_gemm<1, 0, 1024><<<1056, 256, 0, stream>>>(
                nullptr, uph, upl, w1ph, w1pl, in_b, z, xc, dtraw, nullptr);
        } else {
            mfma_gemm<0, 0, 1024><<<1056, 256, 0, stream>>>(
                ub, nullptr, nullptr, w1ph, w1pl, in_b, z, xc, dtraw, nullptr);
        }
        // 2) conv + local chunk scan (xc -> ylocal in R2)
        scanA<<<2048, 64, 0, stream>>>(xc, dtraw, rb, conv_w, conv_b,
                                       dt_bias, A_log, bw, bb,
                                       ylocal, decay, Fb, Eb);
        // 3) cross-chunk scan
        scanB<<<8, 256, 0, stream>>>(Fb, Eb, Sprev);
        // 4) gate + carried state -> y fragment-packed into R1
        passC<<<8192, 256, 0, stream>>>(ylocal, z, Sprev, decay, yph, ypl);
        if (!wonce)
            pack_split<6, 0><<<1024, 256, 0, stream>>>(out_w, 2048, w2ph, w2pl);
        // 5) out_proj (grid 8*4*8, xcd-swizzled)
        mfma_gemm<1, 1, 2048><<<256, 256, 0, stream>>>(
            nullptr, yph, ypl, w2ph, w2pl, nullptr,
            nullptr, nullptr, nullptr, ob);
    }
}